// Round 7
// baseline (252.049 us; speedup 1.0000x reference)
//
#include <hip/hip_runtime.h>
#include <hip/hip_bf16.h>

#define NN 4096
#define DD 256
#define OO 256
#define YT 64
#define NSTEP 32

typedef __attribute__((ext_vector_type(4))) float f32x4;
typedef __attribute__((ext_vector_type(8))) short bf16x8;
typedef __attribute__((ext_vector_type(4))) unsigned int u32x4;

__device__ __forceinline__ short f2bfs(float f) {
    __hip_bfloat16 h = __float2bfloat16(f);
    short s;
    __builtin_memcpy(&s, &h, 2);
    return s;
}

__device__ __forceinline__ void gl_lds16(const float* gsrc, float* ldst) {
    __builtin_amdgcn_global_load_lds(
        (const __attribute__((address_space(1))) void*)gsrc,
        (__attribute__((address_space(3))) void*)ldst,
        16, 0, 0);
}

// K1: XWT[o][m] = sum_k X[m][k] * W[k][o], output bf16, layout [OO][NN] row-major.
__global__ __launch_bounds__(256) void k1_xwt(
    const float* __restrict__ X, const float* __restrict__ W,
    unsigned short* __restrict__ XWT)
{
    __shared__ float xs[16][DD];
    const int t = threadIdx.x;
    const int m0 = blockIdx.x * 16;

    #pragma unroll
    for (int i = 0; i < 16; ++i)
        xs[i][t] = X[(size_t)(m0 + i) * DD + t];
    __syncthreads();

    float acc[16];
    #pragma unroll
    for (int m = 0; m < 16; ++m) acc[m] = 0.f;

    for (int k0 = 0; k0 < DD; k0 += 4) {
        float w0 = W[(size_t)(k0 + 0) * OO + t];
        float w1 = W[(size_t)(k0 + 1) * OO + t];
        float w2 = W[(size_t)(k0 + 2) * OO + t];
        float w3 = W[(size_t)(k0 + 3) * OO + t];
        #pragma unroll
        for (int m = 0; m < 16; ++m) {
            const f32x4 xv = *reinterpret_cast<const f32x4*>(&xs[m][k0]);
            acc[m] = fmaf(xv[0], w0, acc[m]);
            acc[m] = fmaf(xv[1], w1, acc[m]);
            acc[m] = fmaf(xv[2], w2, acc[m]);
            acc[m] = fmaf(xv[3], w3, acc[m]);
        }
    }

    unsigned int p[8];
    #pragma unroll
    for (int i = 0; i < 8; ++i) {
        unsigned lo = (unsigned short)f2bfs(acc[2 * i]);
        unsigned hi = (unsigned short)f2bfs(acc[2 * i + 1]);
        p[i] = lo | (hi << 16);
    }
    u32x4* dst = reinterpret_cast<u32x4*>(XWT + (size_t)t * NN + m0);
    dst[0] = (u32x4){p[0], p[1], p[2], p[3]};
    dst[1] = (u32x4){p[4], p[5], p[6], p[7]};
}

// K2: per (y-tile of 64, n-chunk): LDS-staged streaming of Beta + adjacency.
__global__ __launch_bounds__(512, 4) void k2_fused(
    const float* __restrict__ Beta, const unsigned short* __restrict__ XWT,
    const float* __restrict__ Adj,
    float* __restrict__ gpart, float* __restrict__ apart,
    int clen)
{
    __shared__ float adj_s[2][NSTEP][YT * 3];   // 48 KB
    __shared__ float beta_s[2][NSTEP][YT];      // 16 KB
    __shared__ float lagg[8][YT][3];            // 6 KB

    const int t = threadIdx.x;
    const int lane = t & 63;
    const int w = t >> 6;          // wave 0..7
    const int wo = w & 1;
    const int wy = w >> 1;
    const int g16 = lane >> 4;
    const int r16 = lane & 15;
    const int tile = blockIdx.x;
    const int chunk = blockIdx.y;
    const int y0 = tile * YT;
    const int nbase = chunk * clen;
    const int nsteps = clen / NSTEP;

    const int br = t >> 4, boff = (t & 15) * 4;            // beta: 512 slots
    const int s1 = 512 + t, s2 = 1024 + t;                 // adj: 1536 slots
    const int ar0 = t / 48,  ao0 = (t % 48) * 4;
    const int ar1 = s1 / 48, ao1 = (s1 % 48) * 4;
    const int ar2 = s2 / 48, ao2 = (s2 % 48) * 4;

    #define STAGE(b, gn)                                                            \
        do {                                                                        \
            gl_lds16(Beta + (size_t)((gn) + br) * NN + y0 + boff,                   \
                     &beta_s[b][br][boff]);                                         \
            gl_lds16(Adj + ((size_t)((gn) + ar0) * NN + y0) * 3 + ao0,              \
                     &adj_s[b][ar0][ao0]);                                          \
            gl_lds16(Adj + ((size_t)((gn) + ar1) * NN + y0) * 3 + ao1,              \
                     &adj_s[b][ar1][ao1]);                                          \
            gl_lds16(Adj + ((size_t)((gn) + ar2) * NN + y0) * 3 + ao2,              \
                     &adj_s[b][ar2][ao2]);                                          \
        } while (0)

    STAGE(0, nbase);

    f32x4 acc[8];
    #pragma unroll
    for (int i = 0; i < 8; ++i) acc[i] = (f32x4){0.f, 0.f, 0.f, 0.f};
    float ag0 = 0.f, ag1 = 0.f, ag2 = 0.f;

    const unsigned short* xwbase = XWT + (size_t)(128 * wo + r16) * NN + nbase + 8 * g16;

    __syncthreads();   // drains vmcnt(0): buffer 0 staged

    for (int st = 0; st < nsteps; ++st) {
        const int cur = st & 1;

        bf16x8 bf[8];
        const unsigned short* xp = xwbase + (size_t)st * NSTEP;
        #pragma unroll
        for (int of = 0; of < 8; ++of)
            bf[of] = *reinterpret_cast<const bf16x8*>(xp + (size_t)of * 16 * NN);

        if (st + 1 < nsteps) {
            const int gn = nbase + (st + 1) * NSTEP;
            STAGE(cur ^ 1, gn);
        }

        bf16x8 av;
        #pragma unroll
        for (int j = 0; j < 8; ++j)
            av[j] = f2bfs(beta_s[cur][8 * g16 + j][16 * wy + r16]);

        #pragma unroll
        for (int of = 0; of < 8; ++of)
            acc[of] = __builtin_amdgcn_mfma_f32_16x16x32_bf16(av, bf[of], acc[of], 0, 0, 0);

        #pragma unroll
        for (int i = 0; i < 4; ++i) {
            const int n = 4 * w + i;
            const float bv = beta_s[cur][n][lane];
            ag0 = fmaf(bv, adj_s[cur][n][lane * 3 + 0], ag0);
            ag1 = fmaf(bv, adj_s[cur][n][lane * 3 + 1], ag1);
            ag2 = fmaf(bv, adj_s[cur][n][lane * 3 + 2], ag2);
        }

        __syncthreads();
    }

    lagg[w][lane][0] = ag0;
    lagg[w][lane][1] = ag1;
    lagg[w][lane][2] = ag2;
    __syncthreads();
    if (t < YT * 3) {
        const int yy = t / 3, cc = t % 3;
        float s = 0.f;
        #pragma unroll
        for (int g = 0; g < 8; ++g) s += lagg[g][yy][cc];
        apart[((size_t)chunk * (NN / YT) + tile) * (YT * 3) + t] = s;
    }

    float* gp = gpart + ((size_t)chunk * NN + y0) * OO;
    #pragma unroll
    for (int of = 0; of < 8; ++of) {
        const int o = 128 * wo + 16 * of + r16;
        #pragma unroll
        for (int r = 0; r < 4; ++r) {
            const int yl = 16 * wy + 4 * g16 + r;
            gp[(size_t)yl * OO + o] = acc[of][r];
        }
    }
    #undef STAGE
}

// K3: out[y,o] = sum_ch gpart + (sum_ch apart[y]) @ Wa + bias
__global__ __launch_bounds__(256) void k3_reduce(
    const float* __restrict__ gpart, const float* __restrict__ apart,
    const float* __restrict__ W, const float* __restrict__ bias,
    float* __restrict__ Out, int nchunk)
{
    const int idx = blockIdx.x * 256 + threadIdx.x;   // 0 .. NN*OO/4-1
    const int o = (idx << 2) & (OO - 1);
    const int y = idx >> 6;

    f32x4 acc = {0.f, 0.f, 0.f, 0.f};
    for (int ch = 0; ch < nchunk; ++ch) {
        const f32x4 g = *reinterpret_cast<const f32x4*>(
            &gpart[((size_t)ch * NN + y) * OO + o]);
        acc[0] += g[0]; acc[1] += g[1]; acc[2] += g[2]; acc[3] += g[3];
    }

    float a0 = 0.f, a1 = 0.f, a2 = 0.f;
    const int tile = y >> 6, yl = y & 63;
    for (int ch = 0; ch < nchunk; ++ch) {
        const float* ap = apart + ((size_t)ch * (NN / YT) + tile) * (YT * 3) + yl * 3;
        a0 += ap[0]; a1 += ap[1]; a2 += ap[2];
    }

    #pragma unroll
    for (int j = 0; j < 4; ++j) {
        const int oo = o + j;
        Out[(size_t)y * OO + oo] = acc[j]
            + a0 * W[(size_t)(DD + 0) * OO + oo]
            + a1 * W[(size_t)(DD + 1) * OO + oo]
            + a2 * W[(size_t)(DD + 2) * OO + oo]
            + bias[oo];
    }
}

// ---- probes: read-only bandwidth references over adjacency (2 x 402 MB each) ----
// probeA: grid-stride SWEEP — all blocks walk a common narrow band (copy-shaped).
__global__ __launch_bounds__(256) void probe_sweep(
    const f32x4* __restrict__ src, float* __restrict__ sink)
{
    const int t = threadIdx.x, b = blockIdx.x;
    float s = 0.f;
    #pragma unroll 1
    for (int r = 0; r < 2; ++r) {
        #pragma unroll 1
        for (int i = 0; i < 24; ++i) {
            const f32x4 v = __builtin_nontemporal_load(
                &src[((size_t)i * 2048 + b) * 256 + t]);
            s += v[0] + v[1] + v[2] + v[3];
        }
    }
    sink[(size_t)b * 256 + t] = s;
}

// probeB: PRIVATE contiguous chunk per block (my kernels' shape).
__global__ __launch_bounds__(256) void probe_chunk(
    const f32x4* __restrict__ src, float* __restrict__ sink)
{
    const int t = threadIdx.x, b = blockIdx.x;
    float s = 0.f;
    #pragma unroll 1
    for (int r = 0; r < 2; ++r) {
        #pragma unroll 1
        for (int i = 0; i < 24; ++i) {
            const f32x4 v = __builtin_nontemporal_load(
                &src[((size_t)b * 24 + i) * 256 + t]);
            s += v[0] + v[1] + v[2] + v[3];
        }
    }
    sink[(size_t)b * 256 + t] = s;
}

extern "C" void kernel_launch(void* const* d_in, const int* in_sizes, int n_in,
                              void* d_out, int out_size, void* d_ws, size_t ws_size,
                              hipStream_t stream) {
    (void)in_sizes; (void)n_in; (void)out_size;
    const float* adj  = (const float*)d_in[0];  // (N, N, C)
    const float* X    = (const float*)d_in[1];  // (N, D)
    const float* Beta = (const float*)d_in[2];  // (N, N)
    const float* W    = (const float*)d_in[3];  // (D+C, O)
    const float* bias = (const float*)d_in[4];  // (O)
    float* out = (float*)d_out;                 // (N, O) fp32

    unsigned short* XWT = (unsigned short*)d_ws;       // bf16 [OO][NN], 2 MB
    const size_t xwt_bytes = (size_t)OO * NN * 2;

    const size_t per_chunk = (size_t)NN * OO * 4 + (size_t)(NN / YT) * YT * 3 * 4;
    int nchunk = 4;
    if (ws_size >= xwt_bytes + 8 * per_chunk) nchunk = 8;
    const int clen = NN / nchunk;

    float* gpart = (float*)((char*)d_ws + xwt_bytes);
    float* apart = (float*)((char*)d_ws + xwt_bytes + (size_t)nchunk * NN * OO * 4);

    k1_xwt<<<dim3(NN / 16), dim3(256), 0, stream>>>(X, W, XWT);
    k2_fused<<<dim3(NN / YT, nchunk), dim3(512), 0, stream>>>(
        Beta, XWT, adj, gpart, apart, clen);
    k3_reduce<<<dim3(NN * OO / 4 / 256), dim3(256), 0, stream>>>(
        gpart, apart, W, bias, out, nchunk);

    // bandwidth probes (information-gathering round): write only to a sink at
    // the tail of the workspace, far beyond the 67 MB used above.
    if (ws_size >= (size_t)256 << 20) {
        const size_t off = (ws_size - ((size_t)16 << 20)) & ~(size_t)1023;
        float* sinkA = (float*)((char*)d_ws + off);
        float* sinkB = sinkA + (size_t)2048 * 256;
        probe_sweep<<<dim3(2048), dim3(256), 0, stream>>>(
            (const f32x4*)adj, sinkA);
        probe_chunk<<<dim3(2048), dim3(256), 0, stream>>>(
            (const f32x4*)adj, sinkB);
    }
}

// Round 8
// 186.766 us; speedup vs baseline: 1.3495x; 1.3495x over previous
//
#include <hip/hip_runtime.h>
#include <hip/hip_bf16.h>

#define NN 4096
#define DD 256
#define OO 256
#define NR 4                   // adjacency rows per K2 block
#define ROWF (NN * 3)          // floats per adjacency row
#define NSPLIT 16

typedef __attribute__((ext_vector_type(4))) float f32x4;
typedef __attribute__((ext_vector_type(8))) short bf16x8;
typedef __attribute__((ext_vector_type(4))) unsigned int u32x4;
typedef __attribute__((ext_vector_type(2))) unsigned int u32x2;

__device__ __forceinline__ short f2bfs(float f) {
    __hip_bfloat16 h = __float2bfloat16(f);
    short s;
    __builtin_memcpy(&s, &h, 2);
    return s;
}

__device__ __forceinline__ void gl_lds16(const float* gsrc, float* ldst) {
    __builtin_amdgcn_global_load_lds(
        (const __attribute__((address_space(1))) void*)gsrc,
        (__attribute__((address_space(3))) void*)ldst,
        16, 0, 0);
}

// K1: XWT[o][m] = sum_k X[m][k] * W[k][o], bf16, layout [OO][NN]. 512 blocks.
__global__ __launch_bounds__(256) void k1_xwt(
    const float* __restrict__ X, const float* __restrict__ W,
    unsigned short* __restrict__ XWT)
{
    __shared__ float xs[8][DD];
    const int t = threadIdx.x;
    const int m0 = blockIdx.x * 8;

    #pragma unroll
    for (int i = 0; i < 8; ++i)
        xs[i][t] = X[(size_t)(m0 + i) * DD + t];
    __syncthreads();

    float acc[8];
    #pragma unroll
    for (int m = 0; m < 8; ++m) acc[m] = 0.f;

    for (int k0 = 0; k0 < DD; k0 += 4) {
        float w0 = W[(size_t)(k0 + 0) * OO + t];
        float w1 = W[(size_t)(k0 + 1) * OO + t];
        float w2 = W[(size_t)(k0 + 2) * OO + t];
        float w3 = W[(size_t)(k0 + 3) * OO + t];
        #pragma unroll
        for (int m = 0; m < 8; ++m) {
            const f32x4 xv = *reinterpret_cast<const f32x4*>(&xs[m][k0]);
            acc[m] = fmaf(xv[0], w0, acc[m]);
            acc[m] = fmaf(xv[1], w1, acc[m]);
            acc[m] = fmaf(xv[2], w2, acc[m]);
            acc[m] = fmaf(xv[3], w3, acc[m]);
        }
    }

    unsigned int p[4];
    #pragma unroll
    for (int i = 0; i < 4; ++i) {
        unsigned lo = (unsigned short)f2bfs(acc[2 * i]);
        unsigned hi = (unsigned short)f2bfs(acc[2 * i + 1]);
        p[i] = lo | (hi << 16);
    }
    *reinterpret_cast<u32x4*>(XWT + (size_t)t * NN + m0) = (u32x4){p[0], p[1], p[2], p[3]};
}

// K2: probe-disciplined streamer. Block owns NR=4 adjacency rows.
// Phase 1: stage 4 Beta rows (64KB) to LDS in one dense burst, ONE barrier.
// Phase 2: rolled loop, 3 nontemporal dwordx4 adj loads + 12 FMA per row per
// thread; fixed (y,c) register accumulators; beta from LDS. No further barriers.
// Also emits BetaTb[ch][y][8] bf16 (MFMA A-frag ready) from the staged rows.
__global__ __launch_bounds__(1024, 8) void k2_stream(
    const float* __restrict__ Adj, const float* __restrict__ Beta,
    float* __restrict__ apart, unsigned short* __restrict__ BetaTb)
{
    __shared__ float bsm[NR * NN];   // 64 KB
    const int t = threadIdx.x;
    const int nb = blockIdx.x;       // 0..1023
    const int n0 = nb * NR;
    const int ch = nb >> 1;          // BetaTb chunk (8 rows)
    const int jb = (nb & 1) * 4;     // j-offset within chunk

    int fpos[3], y0[3], rr[3];
    #pragma unroll
    for (int p = 0; p < 3; ++p) {
        fpos[p] = p * NN + 4 * t;
        y0[p] = fpos[p] / 3;
        rr[p] = fpos[p] - 3 * y0[p];
    }

    // phase 1: dense beta staging (lane-linear LDS dest, wave-uniform base)
    #pragma unroll
    for (int i = 0; i < NR; ++i)
        gl_lds16(Beta + (size_t)(n0 + i) * NN + 4 * t, bsm + i * NN + 4 * t);
    __syncthreads();

    f32x4 acc[3];
    #pragma unroll
    for (int p = 0; p < 3; ++p) acc[p] = (f32x4){0.f, 0.f, 0.f, 0.f};
    unsigned int bb[3][NR];

    const float* arow = Adj + (size_t)n0 * ROWF;
    #pragma unroll 1
    for (int n = 0; n < NR; ++n) {
        f32x4 av[3];
        #pragma unroll
        for (int p = 0; p < 3; ++p)
            av[p] = __builtin_nontemporal_load(
                reinterpret_cast<const f32x4*>(arow + fpos[p]));
        #pragma unroll
        for (int p = 0; p < 3; ++p) {
            const float bl = bsm[n * NN + y0[p]];
            const float bh = bsm[n * NN + y0[p] + 1];
            #pragma unroll
            for (int q = 0; q < 4; ++q) {
                const float w = (rr[p] + q < 3) ? bl : bh;
                acc[p][q] = fmaf(w, av[p][q], acc[p][q]);
            }
            bb[p][n] = (unsigned)(unsigned short)f2bfs(bl)
                     | ((unsigned)(unsigned short)f2bfs(bh) << 16);
        }
        arow += ROWF;
    }

    // adjacency partial: 3 coalesced x4 stores
    float* op = apart + (size_t)nb * ROWF;
    #pragma unroll
    for (int p = 0; p < 3; ++p)
        *reinterpret_cast<f32x4*>(op + fpos[p]) = acc[p];

    // BetaTb: 4 n-consecutive bf16 for y0[p] (lo halves) and y0[p]+1 (hi halves).
    // Neighboring threads may write the same y twice with identical bytes - benign.
    #pragma unroll
    for (int p = 0; p < 3; ++p) {
        const unsigned lo0 = (bb[p][0] & 0xffffu) | (bb[p][1] << 16);
        const unsigned lo1 = (bb[p][2] & 0xffffu) | (bb[p][3] << 16);
        const unsigned hi0 = (bb[p][0] >> 16) | (bb[p][1] & 0xffff0000u);
        const unsigned hi1 = (bb[p][2] >> 16) | (bb[p][3] & 0xffff0000u);
        unsigned short* d0 = BetaTb + ((size_t)ch * NN + y0[p]) * 8 + jb;
        unsigned short* d1 = BetaTb + ((size_t)ch * NN + y0[p] + 1) * 8 + jb;
        *reinterpret_cast<u32x2*>(d0) = (u32x2){lo0, lo1};
        *reinterpret_cast<u32x2*>(d1) = (u32x2){hi0, hi1};
    }
}

// K2b phase 1: agg2[by][i] = sum of 256 consecutive n-blocks. grid (48, 4).
__global__ __launch_bounds__(256) void k2b_reduce(
    const float* __restrict__ apart, float* __restrict__ agg2)
{
    const int i = blockIdx.x * 256 + threadIdx.x;   // 0 .. ROWF-1
    const int by = blockIdx.y;
    float s = 0.f;
    #pragma unroll 4
    for (int b2 = 0; b2 < 256; ++b2)
        s += apart[(size_t)(by * 256 + b2) * ROWF + i];
    agg2[(size_t)by * ROWF + i] = s;
}

// K4: gpart[sp][y][o] = sum_{n in split} Beta[n,y]*XW[n,o], all-bf16 dense loads.
// grid (64 y-blocks, NSPLIT), 256 thr = 4 waves (structure proven in r5/r6).
__global__ __launch_bounds__(256) void k4_gemm(
    const unsigned short* __restrict__ BetaTb, const unsigned short* __restrict__ XWT,
    float* __restrict__ gpart, int clen)
{
    const int t = threadIdx.x;
    const int lane = t & 63;
    const int w = t >> 6;
    const int g16 = lane >> 4, r16 = lane & 15;
    const int y0 = blockIdx.x * 64 + 16 * w;
    const int sp = blockIdx.y;
    const int nb = sp * clen;
    const int ksteps = clen / 32;

    f32x4 acc[16];
    #pragma unroll
    for (int f = 0; f < 16; ++f) acc[f] = (f32x4){0.f, 0.f, 0.f, 0.f};

    for (int kc = 0; kc < ksteps; ++kc) {
        const int n0 = nb + kc * 32;
        const bf16x8 av = *reinterpret_cast<const bf16x8*>(
            BetaTb + ((size_t)(n0 / 8 + g16) * NN + y0 + r16) * 8);
        const unsigned short* xp = XWT + (size_t)r16 * NN + n0 + 8 * g16;
        #pragma unroll
        for (int f = 0; f < 16; ++f) {
            const bf16x8 bv = *reinterpret_cast<const bf16x8*>(xp + (size_t)16 * f * NN);
            acc[f] = __builtin_amdgcn_mfma_f32_16x16x32_bf16(av, bv, acc[f], 0, 0, 0);
        }
    }

    float* gp = gpart + (size_t)sp * NN * OO;
    #pragma unroll
    for (int f = 0; f < 16; ++f) {
        const int o = 16 * f + r16;
        #pragma unroll
        for (int r = 0; r < 4; ++r)
            gp[(size_t)(y0 + 4 * g16 + r) * OO + o] = acc[f][r];
    }
}

// K3: out[y,o] = sum_sp gpart + (sum_s agg2[s][y]) @ Wa + bias
__global__ __launch_bounds__(256) void k3_final(
    const float* __restrict__ gpart, const float* __restrict__ agg2,
    const float* __restrict__ W, const float* __restrict__ bias,
    float* __restrict__ Out, int nsplit)
{
    const int idx = blockIdx.x * 256 + threadIdx.x;   // 0 .. NN*OO/4-1
    const int y = idx >> 6;
    const int o = (idx & 63) * 4;

    f32x4 acc = {0.f, 0.f, 0.f, 0.f};
    for (int sp = 0; sp < nsplit; ++sp) {
        const f32x4 g = *reinterpret_cast<const f32x4*>(
            &gpart[(size_t)sp * NN * OO + (size_t)y * OO + o]);
        acc[0] += g[0]; acc[1] += g[1]; acc[2] += g[2]; acc[3] += g[3];
    }

    float a0 = 0.f, a1 = 0.f, a2 = 0.f;
    #pragma unroll
    for (int s = 0; s < 4; ++s) {
        a0 += agg2[(size_t)s * ROWF + y * 3 + 0];
        a1 += agg2[(size_t)s * ROWF + y * 3 + 1];
        a2 += agg2[(size_t)s * ROWF + y * 3 + 2];
    }

    #pragma unroll
    for (int j = 0; j < 4; ++j) {
        const int oo = o + j;
        Out[(size_t)y * OO + oo] = acc[j]
            + a0 * W[(size_t)(DD + 0) * OO + oo]
            + a1 * W[(size_t)(DD + 1) * OO + oo]
            + a2 * W[(size_t)(DD + 2) * OO + oo]
            + bias[oo];
    }
}

extern "C" void kernel_launch(void* const* d_in, const int* in_sizes, int n_in,
                              void* d_out, int out_size, void* d_ws, size_t ws_size,
                              hipStream_t stream) {
    (void)in_sizes; (void)n_in; (void)out_size;
    const float* adj  = (const float*)d_in[0];  // (N, N, C)
    const float* X    = (const float*)d_in[1];  // (N, D)
    const float* Beta = (const float*)d_in[2];  // (N, N)
    const float* W    = (const float*)d_in[3];  // (D+C, O)
    const float* bias = (const float*)d_in[4];  // (O)
    float* out = (float*)d_out;                 // (N, O) fp32

    const size_t xwt_b   = (size_t)OO * NN * 2;              // 2 MB
    const size_t betat_b = (size_t)NN * NN * 2;              // 32 MB
    const size_t apart_b = (size_t)(NN / NR) * ROWF * 4;     // 48 MB
    const size_t agg2_b  = (size_t)4 * ROWF * 4;             // 192 KB

    int nsplit = NSPLIT;
    size_t gpart_b = (size_t)nsplit * NN * OO * 4;           // 64 MB
    if (ws_size < xwt_b + betat_b + apart_b + agg2_b + gpart_b) {
        nsplit = 4;
        gpart_b = (size_t)nsplit * NN * OO * 4;
    }

    char* p = (char*)d_ws;
    unsigned short* XWT    = (unsigned short*)p;            p += xwt_b;
    unsigned short* BetaTb = (unsigned short*)p;            p += betat_b;
    float*          gpart  = (float*)p;                     p += gpart_b;
    float*          apart  = (float*)p;                     p += apart_b;
    float*          agg2   = (float*)p;

    const int clen = NN / nsplit;

    k1_xwt<<<dim3(NN / 8), dim3(256), 0, stream>>>(X, W, XWT);
    k2_stream<<<dim3(NN / NR), dim3(1024), 0, stream>>>(adj, Beta, apart, BetaTb);
    k2b_reduce<<<dim3(ROWF / 256, 4), dim3(256), 0, stream>>>(apart, agg2);
    k4_gemm<<<dim3(NN / 64, nsplit), dim3(256), 0, stream>>>(BetaTb, XWT, gpart, clen);
    k3_final<<<dim3(NN * OO / 4 / 256), dim3(256), 0, stream>>>(
        gpart, agg2, W, bias, out, nsplit);
}